// Round 11
// baseline (184.225 us; speedup 1.0000x reference)
//
#include <hip/hip_runtime.h>
#include <hip/hip_bf16.h>

// Linformer MHA, MI355X gfx950. Round 11: dbuf-prefetch K-loop in gemm97
// (2-phase: issue next K-step's global_load_lds BEFORE computing current —
// same structure that won attn in round 9). Everything else = round 10.
// Pipeline (stream-ordered aliasing, ws = 32MB exactly):
//   k_convert_a: q,k,v -> Xqb[0:4M) Xkb[4M:8M) Xvb[8M:12M); Wq/Wk/Wv/Wo -> [12M:16M)
//   k_kv   : K/V projections -> KbT/VbT in d_out
//   k_q    : Q projection -> Qb @ [4M:8M)
//   k_convert_b: WkP/WvP -> [8M:12M)
//   k_linproj: -> Kp[0:2M) VpT[2M:4M)
//   attn   : -> Xo[8M:12M)
//   k_outproj: -> fp32 d_out

typedef __attribute__((ext_vector_type(4))) float  f32x4;
typedef __attribute__((ext_vector_type(8))) short  short8;
typedef __attribute__((ext_vector_type(4))) short  short4_t;
typedef __attribute__((ext_vector_type(8))) __bf16 bf16x8;
typedef unsigned short ushort_t;

#define DEV __device__ __forceinline__

constexpr int B_ = 2, S_ = 2048, D_ = 1024, H_ = 16, SP_ = 1024;
constexpr size_t M1 = 1u << 20;
constexpr size_t XQ_OFF = 0,      XK_OFF = 4*M1,  XV_OFF = 8*M1,
                 WQ_OFF = 12*M1,  WK_OFF = 13*M1, WV_OFF = 14*M1, WO_OFF = 15*M1,
                 QB_OFF = 4*M1,   KP_OFF = 0,     VPT_OFF = 2*M1,
                 WKPB_OFF = 8*M1, WVPB_OFF = 10*M1, XO_OFF = 8*M1;

DEV ushort_t f2bf(float f) {              // RNE fp32 -> bf16 bits
  unsigned u = __builtin_bit_cast(unsigned, f);
  unsigned r = ((u >> 16) & 1u) + 0x7FFFu;
  return (ushort_t)((u + r) >> 16);
}
DEV bf16x8 ld8(const ushort_t* p) {
  return __builtin_bit_cast(bf16x8, *reinterpret_cast<const short8*>(p));
}
DEV f32x4 mfma16(bf16x8 a, bf16x8 b, f32x4 c) {
  return __builtin_amdgcn_mfma_f32_16x16x32_bf16(a, b, c, 0, 0, 0);
}
DEV void gload16(const ushort_t* g, ushort_t* l) {   // 16B global -> LDS direct
  __builtin_amdgcn_global_load_lds(
      (const __attribute__((address_space(1))) void*)g,
      (__attribute__((address_space(3))) void*)l, 16, 0, 0);
}
DEV void cvt2048(const float* src, ushort_t* dst, int tid) {
  const size_t off = (size_t)tid * 8;
  float4 f0 = *reinterpret_cast<const float4*>(src + off);
  float4 f1 = *reinterpret_cast<const float4*>(src + off + 4);
  ushort_t t[8] = { f2bf(f0.x), f2bf(f0.y), f2bf(f0.z), f2bf(f0.w),
                    f2bf(f1.x), f2bf(f1.y), f2bf(f1.z), f2bf(f1.w) };
  *reinterpret_cast<short8*>(dst + off) = *reinterpret_cast<short8*>(t);
}

// ---------------------------------------------------------------------------
// Conversion A: q,k,v (12M) + Wq,Wk,Wv,Wo (4M) -> bf16. 8192 blocks x 2048 el.
// ---------------------------------------------------------------------------
__global__ __launch_bounds__(256) void k_convert_a(
    const float* __restrict__ q, const float* __restrict__ k,
    const float* __restrict__ v, const float* __restrict__ Wq,
    const float* __restrict__ Wk, const float* __restrict__ Wv,
    const float* __restrict__ Wo, ushort_t* __restrict__ ws)
{
  int blk = blockIdx.x; const float* src; ushort_t* dst;
  if      (blk < 2048) { src = q;  dst = ws + XQ_OFF; }
  else if (blk < 4096) { src = k;  dst = ws + XK_OFF; blk -= 2048; }
  else if (blk < 6144) { src = v;  dst = ws + XV_OFF; blk -= 4096; }
  else if (blk < 6656) { src = Wq; dst = ws + WQ_OFF; blk -= 6144; }
  else if (blk < 7168) { src = Wk; dst = ws + WK_OFF; blk -= 6656; }
  else if (blk < 7680) { src = Wv; dst = ws + WV_OFF; blk -= 7168; }
  else                 { src = Wo; dst = ws + WO_OFF; blk -= 7680; }
  cvt2048(src + (size_t)blk * 2048, dst + (size_t)blk * 2048, threadIdx.x);
}

// Conversion B: WkP, WvP (4M elems) -> bf16. 2048 blocks.
__global__ __launch_bounds__(256) void k_convert_b(
    const float* __restrict__ WkP, const float* __restrict__ WvP,
    ushort_t* __restrict__ ws)
{
  int blk = blockIdx.x; const float* src; ushort_t* dst;
  if (blk < 1024) { src = WkP; dst = ws + WKPB_OFF; }
  else            { src = WvP; dst = ws + WVPB_OFF; blk -= 1024; }
  cvt2048(src + (size_t)blk * 2048, dst + (size_t)blk * 2048, threadIdx.x);
}

// ---------------------------------------------------------------------------
// m97-style 128x128x(K) bf16 MFMA GEMM, 256 thr (4 waves, 2x2), linear LDS,
// global_load_lds both operands, DOUBLE-BUFFERED K-loop (prefetch-then-compute,
// one barrier per K-step; prefetch latency hides under the 16 MFMAs).
// OUTMODE: 0 bf16 C[m][n]; 1 fp32 C[m][n]; 2 bf16 Ct[b][n][s] (s strided S_);
//          3 bf16 Ct[n][m] (stride M).
// ---------------------------------------------------------------------------
template<int BIAS, int EPI, int OUTMODE>
DEV void gemm97(const ushort_t* Ap, const ushort_t* Bp, const float* bias,
                const int* mask, void* Cp, int M, int N, int K)
{
  __shared__ __align__(16) ushort_t As[2][128 * 32];
  __shared__ __align__(16) ushort_t Bs[2][128 * 32];
  const int tid = threadIdx.x;
  const int m0 = blockIdx.x * 128, n0 = blockIdx.y * 128;
  const int w = tid >> 6, lane = tid & 63, lr = lane & 15, lg = lane >> 4;
  const int wm = (w >> 1) * 64, wn = (w & 1) * 64;

  f32x4 acc[4][4];
#pragma unroll
  for (int i = 0; i < 4; ++i)
#pragma unroll
    for (int j = 0; j < 4; ++j) acc[i][j] = f32x4{0.f, 0.f, 0.f, 0.f};

  const int gr = tid >> 2, gc = (tid & 3) * 8;       // gload staging map
  const ushort_t* Ag0 = Ap + (size_t)(m0 + gr) * K + gc;
  const ushort_t* Ag1 = Ap + (size_t)(m0 + 64 + gr) * K + gc;
  const ushort_t* Bg0 = Bp + (size_t)(n0 + gr) * K + gc;
  const ushort_t* Bg1 = Bp + (size_t)(n0 + 64 + gr) * K + gc;

  // prologue: stage K-step 0 into buffer 0
  gload16(Ag0, As[0] + tid*8);
  gload16(Ag1, As[0] + 64*32 + tid*8);
  gload16(Bg0, Bs[0] + tid*8);
  gload16(Bg1, Bs[0] + 64*32 + tid*8);
  __syncthreads();

  int cur = 0;
  for (int k0 = 0; k0 < K; k0 += 32) {
    // issue next K-step's staging first (overlaps with MFMA below)
    if (k0 + 32 < K) {
      const int kn = k0 + 32;
      gload16(Ag0 + kn, As[cur^1] + tid*8);
      gload16(Ag1 + kn, As[cur^1] + 64*32 + tid*8);
      gload16(Bg0 + kn, Bs[cur^1] + tid*8);
      gload16(Bg1 + kn, Bs[cur^1] + 64*32 + tid*8);
    }

    bf16x8 af[4], bfv[4];
#pragma unroll
    for (int i = 0; i < 4; ++i) af[i]  = ld8(&As[cur][(wm + i*16 + lr)*32 + 8*lg]);
#pragma unroll
    for (int j = 0; j < 4; ++j) bfv[j] = ld8(&Bs[cur][(wn + j*16 + lr)*32 + 8*lg]);
#pragma unroll
    for (int i = 0; i < 4; ++i)
#pragma unroll
      for (int j = 0; j < 4; ++j)
        acc[i][j] = mfma16(af[i], bfv[j], acc[i][j]);

    __syncthreads();   // waves done with buf cur; prefetch (to cur^1) drained
    cur ^= 1;
  }

#pragma unroll
  for (int i = 0; i < 4; ++i) {
    const int mBase = m0 + wm + i*16 + 4*lg;
#pragma unroll
    for (int j = 0; j < 4; ++j) {
      const int n = n0 + wn + j*16 + lr;
      float vv[4];
#pragma unroll
      for (int r = 0; r < 4; ++r) {
        const int m = mBase + r;
        float v = acc[i][j][r];
        if (BIAS == 2) v += bias[n];
        if (BIAS == 1) v += bias[m];
        if (EPI == 1)  v = mask[m] ? v : 0.f;
        if (EPI == 2)  v = 0.5f * v * (1.f + erff(v * 0.70710678118654752f));
        vv[r] = v;
      }
      if (OUTMODE == 0) {
#pragma unroll
        for (int r = 0; r < 4; ++r)
          ((ushort_t*)Cp)[(size_t)(mBase + r) * N + n] = f2bf(vv[r]);
      } else if (OUTMODE == 1) {
#pragma unroll
        for (int r = 0; r < 4; ++r)
          ((float*)Cp)[(size_t)(mBase + r) * N + n] = vv[r];
      } else if (OUTMODE == 2) {       // Ct[b][n][s], s=m-b*S_ (K/V proj path)
        const int bb = mBase >> 11;
        const int sb = mBase & (S_ - 1);
        ushort_t t4[4] = { f2bf(vv[0]), f2bf(vv[1]), f2bf(vv[2]), f2bf(vv[3]) };
        *reinterpret_cast<short4_t*>(
            (ushort_t*)Cp + ((size_t)bb * D_ + n) * S_ + sb) =
            *reinterpret_cast<short4_t*>(t4);
      } else {                         // Ct[n][m], stride M (linproj V path)
        ushort_t t4[4] = { f2bf(vv[0]), f2bf(vv[1]), f2bf(vv[2]), f2bf(vv[3]) };
        *reinterpret_cast<short4_t*>(
            (ushort_t*)Cp + (size_t)n * M + mBase) =
            *reinterpret_cast<short4_t*>(t4);
      }
    }
  }
}

// --------------------------- kernel wrappers -------------------------------
__global__ __launch_bounds__(256) void k_kv(
    const float* __restrict__ bk, const float* __restrict__ bv,
    const int* __restrict__ mask, const ushort_t* __restrict__ ws,
    ushort_t* __restrict__ KbT, ushort_t* __restrict__ VbT)
{
  if (blockIdx.z == 0)
    gemm97<2, 1, 2>(ws + XK_OFF, ws + WK_OFF, bk, mask, KbT, B_*S_, D_, D_);
  else
    gemm97<2, 1, 2>(ws + XV_OFF, ws + WV_OFF, bv, mask, VbT, B_*S_, D_, D_);
}

__global__ __launch_bounds__(256) void k_q(
    const float* __restrict__ bq, const int* __restrict__ mask,
    const ushort_t* __restrict__ ws, ushort_t* __restrict__ Qb)
{
  gemm97<2, 1, 0>(ws + XQ_OFF, ws + WQ_OFF, bq, mask, Qb, B_*S_, D_, D_);
}

__global__ __launch_bounds__(256) void k_linproj(
    const float* __restrict__ bkP, const float* __restrict__ bvP,
    const ushort_t* __restrict__ ws, const ushort_t* __restrict__ KbT,
    const ushort_t* __restrict__ VbT, ushort_t* __restrict__ Kp,
    ushort_t* __restrict__ VpT)
{
  const int z = blockIdx.z, b = z >> 1, isv = z & 1;
  if (isv) {
    gemm97<1, 2, 3>(ws + WVPB_OFF, VbT + (size_t)b * D_ * S_, bvP,
                    nullptr, VpT + (size_t)b * D_ * SP_, SP_, D_, S_);
  } else {
    gemm97<1, 2, 0>(ws + WKPB_OFF, KbT + (size_t)b * D_ * S_, bkP,
                    nullptr, Kp + (size_t)b * SP_ * D_, SP_, D_, S_);
  }
}

__global__ __launch_bounds__(256) void k_outproj(
    const ushort_t* __restrict__ Xo, const ushort_t* __restrict__ Wob,
    const float* __restrict__ bo, float* __restrict__ out)
{
  gemm97<2, 0, 1>(Xo, Wob, bo, nullptr, out, B_*S_, D_, D_);
}

// ---------------------------------------------------------------------------
// Fused attention (round-9 structure, unchanged): 512 thr, QBLK=128, KVBLK=64,
// LDS-staged K/V^T (gload, dbuf, XOR swizzle), fixed-max softmax.
// ---------------------------------------------------------------------------
__global__ __launch_bounds__(512) void attn_kernel(
    const ushort_t* __restrict__ Qb, const ushort_t* __restrict__ Kp,
    const ushort_t* __restrict__ VpT, ushort_t* __restrict__ Xo)
{
  __shared__ __align__(16) ushort_t Ks[2][64 * 64];
  __shared__ __align__(16) ushort_t Vs[2][64 * 64];
  __shared__ __align__(16) ushort_t Pl[8][16][72];

  const int b = blockIdx.z, h = blockIdx.y, s0 = blockIdx.x * 128;
  const int tid = threadIdx.x, w = tid >> 6, lane = tid & 63;
  const int lr = lane & 15, lg = lane >> 4;

  const ushort_t* qp = Qb + (size_t)(b * S_ + s0 + w*16 + lr) * D_ + h * 64;
  const bf16x8 aq0 = ld8(qp + 8*lg);
  const bf16x8 aq1 = ld8(qp + 32 + 8*lg);

  const ushort_t* kbase = Kp  + (size_t)b * SP_ * D_ + h * 64;
  const ushort_t* vbase = VpT + (size_t)b * D_ * SP_ + (size_t)(h*64) * SP_;

  const int srow = tid >> 3, sch = tid & 7;
  const int schx = (sch ^ (srow & 7)) << 3;

  f32x4 o[4];
#pragma unroll
  for (int dt = 0; dt < 4; ++dt) o[dt] = f32x4{0.f, 0.f, 0.f, 0.f};
  float lsum[4] = {0.f, 0.f, 0.f, 0.f};
  constexpr float C_ = 0.18033688011112042f;          // 0.125 * log2(e)

  gload16(kbase + (size_t)srow * D_ + schx, Ks[0] + tid*8);
  gload16(vbase + (size_t)srow * SP_ + schx, Vs[0] + tid*8);
  __syncthreads();

  int cur = 0;
  for (int pt = 0; pt < SP_ / 64; ++pt) {
    if (pt + 1 < SP_ / 64) {
      const int p1 = (pt + 1) * 64;
      gload16(kbase + (size_t)(p1 + srow) * D_ + schx, Ks[cur^1] + tid*8);
      gload16(vbase + (size_t)srow * SP_ + p1 + schx, Vs[cur^1] + tid*8);
    }

    const int rk7 = lr & 7;
#pragma unroll
    for (int nt = 0; nt < 4; ++nt) {
      const ushort_t* krow = Ks[cur] + (nt*16 + lr) * 64;
      f32x4 a = f32x4{0.f, 0.f, 0.f, 0.f};
      a = mfma16(aq0, ld8(krow + ((lg       ^ rk7) << 3)), a);
      a = mfma16(aq1, ld8(krow + (((4 + lg) ^ rk7) << 3)), a);
#pragma unroll
      for (int r = 0; r < 4; ++r) {
        const float p = __builtin_exp2f(a[r] * C_);
        lsum[r] += p;
        Pl[w][4*lg + r][nt*16 + lr] =
            __builtin_bit_cast(ushort_t, __float2bfloat16(p));
      }
    }

    const bf16x8 pa0 = ld8(&Pl[w][lr][8*lg]);
    const bf16x8 pa1 = ld8(&Pl[w][lr][32 + 8*lg]);
#pragma unroll
    for (int dt = 0; dt < 4; ++dt) {
      const ushort_t* vrow = Vs[cur] + (dt*16 + lr) * 64;
      o[dt] = mfma16(pa0, ld8(vrow + ((lg       ^ rk7) << 3)), o[dt]);
      o[dt] = mfma16(pa1, ld8(vrow + (((4 + lg) ^ rk7) << 3)), o[dt]);
    }

    __syncthreads();
    cur ^= 1;
  }

#pragma unroll
  for (int r = 0; r < 4; ++r) {
#pragma unroll
    for (int off2 = 1; off2 < 16; off2 <<= 1)
      lsum[r] += __shfl_xor(lsum[r], off2, 64);
    lsum[r] = 1.f / lsum[r];
  }

#pragma unroll
  for (int dt = 0; dt < 4; ++dt)
#pragma unroll
    for (int r = 0; r < 4; ++r) {
      const int srow2 = s0 + w*16 + 4*lg + r;
      Xo[(size_t)(b * S_ + srow2) * D_ + h*64 + dt*16 + lr] =
          f2bf(o[dt][r] * lsum[r]);
    }
}

// ------------------------------- launch ------------------------------------
extern "C" void kernel_launch(void* const* d_in, const int* in_sizes, int n_in,
                              void* d_out, int out_size, void* d_ws, size_t ws_size,
                              hipStream_t stream)
{
  const float* q   = (const float*)d_in[0];
  const float* k   = (const float*)d_in[1];
  const float* v   = (const float*)d_in[2];
  const int*   msk = (const int*)d_in[3];
  const float* Wq  = (const float*)d_in[4];
  const float* bq  = (const float*)d_in[5];
  const float* Wk  = (const float*)d_in[6];
  const float* bk  = (const float*)d_in[7];
  const float* Wv  = (const float*)d_in[8];
  const float* bv  = (const float*)d_in[9];
  const float* Wo  = (const float*)d_in[10];
  const float* bo  = (const float*)d_in[11];
  const float* WkP = (const float*)d_in[12];
  const float* bkP = (const float*)d_in[13];
  const float* WvP = (const float*)d_in[14];
  const float* bvP = (const float*)d_in[15];

  ushort_t* ws  = (ushort_t*)d_ws;
  ushort_t* Qb  = ws + QB_OFF;
  ushort_t* Kp  = ws + KP_OFF;
  ushort_t* VpT = ws + VPT_OFF;
  ushort_t* Xo  = ws + XO_OFF;
  ushort_t* KbT = (ushort_t*)d_out;     // d_out as scratch until k_outproj
  ushort_t* VbT = KbT + 4 * M1;

  dim3 blk(256, 1, 1);
  k_convert_a<<<dim3(8192, 1, 1), blk, 0, stream>>>(q, k, v, Wq, Wk, Wv, Wo, ws);
  k_kv     <<<dim3(B_*S_/128, D_/128, 2), blk, 0, stream>>>(bk, bv, msk, ws, KbT, VbT);
  k_q      <<<dim3(B_*S_/128, D_/128, 1), blk, 0, stream>>>(bq, msk, ws, Qb);
  k_convert_b<<<dim3(2048, 1, 1), blk, 0, stream>>>(WkP, WvP, ws);
  k_linproj<<<dim3(SP_/128,  D_/128, 4), blk, 0, stream>>>(bkP, bvP, ws, KbT, VbT, Kp, VpT);
  attn_kernel<<<dim3(S_/128, H_, B_), dim3(512,1,1), 0, stream>>>(Qb, Kp, VpT, Xo);
  k_outproj<<<dim3(B_*S_/128, D_/128, 1), blk, 0, stream>>>(Xo, ws + WO_OFF, bo, (float*)d_out);
}

// Round 12
// 171.198 us; speedup vs baseline: 1.0761x; 1.0761x over previous
//
#include <hip/hip_runtime.h>
#include <hip/hip_bf16.h>

// Linformer MHA, MI355X gfx950. Round 12: single-buffer gemmT with 64x128
// tiles -> 2-4 blocks/CU (TLP hides the barrier drain; dbuf reverted, round-11
// showed __syncthreads drains the prefetch anyway = m99/m100 null result).
// Pipeline (stream-ordered aliasing, ws = 32MB exactly):
//   k_convert_a: q,k,v -> Xqb[0:4M) Xkb[4M:8M) Xvb[8M:12M); Wq/Wk/Wv/Wo -> [12M:16M)
//   k_kv   : K/V projections -> KbT/VbT in d_out
//   k_q    : Q projection -> Qb @ [4M:8M)
//   k_convert_b: WkP/WvP -> [8M:12M)
//   k_linproj: -> Kp[0:2M) VpT[2M:4M)
//   attn   : -> Xo[8M:12M)
//   k_outproj: -> fp32 d_out

typedef __attribute__((ext_vector_type(4))) float  f32x4;
typedef __attribute__((ext_vector_type(8))) short  short8;
typedef __attribute__((ext_vector_type(4))) short  short4_t;
typedef __attribute__((ext_vector_type(8))) __bf16 bf16x8;
typedef unsigned short ushort_t;

#define DEV __device__ __forceinline__

constexpr int B_ = 2, S_ = 2048, D_ = 1024, H_ = 16, SP_ = 1024;
constexpr size_t M1 = 1u << 20;
constexpr size_t XQ_OFF = 0,      XK_OFF = 4*M1,  XV_OFF = 8*M1,
                 WQ_OFF = 12*M1,  WK_OFF = 13*M1, WV_OFF = 14*M1, WO_OFF = 15*M1,
                 QB_OFF = 4*M1,   KP_OFF = 0,     VPT_OFF = 2*M1,
                 WKPB_OFF = 8*M1, WVPB_OFF = 10*M1, XO_OFF = 8*M1;

DEV ushort_t f2bf(float f) {              // RNE fp32 -> bf16 bits
  unsigned u = __builtin_bit_cast(unsigned, f);
  unsigned r = ((u >> 16) & 1u) + 0x7FFFu;
  return (ushort_t)((u + r) >> 16);
}
DEV bf16x8 ld8(const ushort_t* p) {
  return __builtin_bit_cast(bf16x8, *reinterpret_cast<const short8*>(p));
}
DEV f32x4 mfma16(bf16x8 a, bf16x8 b, f32x4 c) {
  return __builtin_amdgcn_mfma_f32_16x16x32_bf16(a, b, c, 0, 0, 0);
}
DEV void gload16(const ushort_t* g, ushort_t* l) {   // 16B global -> LDS direct
  __builtin_amdgcn_global_load_lds(
      (const __attribute__((address_space(1))) void*)g,
      (__attribute__((address_space(3))) void*)l, 16, 0, 0);
}
DEV void cvt2048(const float* src, ushort_t* dst, int tid) {
  const size_t off = (size_t)tid * 8;
  float4 f0 = *reinterpret_cast<const float4*>(src + off);
  float4 f1 = *reinterpret_cast<const float4*>(src + off + 4);
  ushort_t t[8] = { f2bf(f0.x), f2bf(f0.y), f2bf(f0.z), f2bf(f0.w),
                    f2bf(f1.x), f2bf(f1.y), f2bf(f1.z), f2bf(f1.w) };
  *reinterpret_cast<short8*>(dst + off) = *reinterpret_cast<short8*>(t);
}

// ---------------------------------------------------------------------------
// Conversion A: q,k,v (12M) + Wq,Wk,Wv,Wo (4M) -> bf16. 8192 blocks x 2048 el.
// ---------------------------------------------------------------------------
__global__ __launch_bounds__(256) void k_convert_a(
    const float* __restrict__ q, const float* __restrict__ k,
    const float* __restrict__ v, const float* __restrict__ Wq,
    const float* __restrict__ Wk, const float* __restrict__ Wv,
    const float* __restrict__ Wo, ushort_t* __restrict__ ws)
{
  int blk = blockIdx.x; const float* src; ushort_t* dst;
  if      (blk < 2048) { src = q;  dst = ws + XQ_OFF; }
  else if (blk < 4096) { src = k;  dst = ws + XK_OFF; blk -= 2048; }
  else if (blk < 6144) { src = v;  dst = ws + XV_OFF; blk -= 4096; }
  else if (blk < 6656) { src = Wq; dst = ws + WQ_OFF; blk -= 6144; }
  else if (blk < 7168) { src = Wk; dst = ws + WK_OFF; blk -= 6656; }
  else if (blk < 7680) { src = Wv; dst = ws + WV_OFF; blk -= 7168; }
  else                 { src = Wo; dst = ws + WO_OFF; blk -= 7680; }
  cvt2048(src + (size_t)blk * 2048, dst + (size_t)blk * 2048, threadIdx.x);
}

// Conversion B: WkP, WvP (4M elems) -> bf16. 2048 blocks.
__global__ __launch_bounds__(256) void k_convert_b(
    const float* __restrict__ WkP, const float* __restrict__ WvP,
    ushort_t* __restrict__ ws)
{
  int blk = blockIdx.x; const float* src; ushort_t* dst;
  if (blk < 1024) { src = WkP; dst = ws + WKPB_OFF; }
  else            { src = WvP; dst = ws + WVPB_OFF; blk -= 1024; }
  cvt2048(src + (size_t)blk * 2048, dst + (size_t)blk * 2048, threadIdx.x);
}

// ---------------------------------------------------------------------------
// 64x128x(K) bf16 MFMA GEMM, 256 thr (4 waves; each wave 32x64 = 2x4 frags),
// single-buffered linear LDS (12KB), global_load_lds both operands.
// Grid is 2-4x the 128x128 version -> 2-4 blocks/CU for latency hiding.
// OUTMODE: 0 bf16 C[m][n]; 1 fp32 C[m][n]; 2 bf16 Ct[b][n][s] (s strided S_);
//          3 bf16 Ct[n][m] (stride M).
// ---------------------------------------------------------------------------
template<int BIAS, int EPI, int OUTMODE>
DEV void gemmT(const ushort_t* Ap, const ushort_t* Bp, const float* bias,
               const int* mask, void* Cp, int M, int N, int K)
{
  __shared__ __align__(16) ushort_t As[64 * 32];    // 4KB
  __shared__ __align__(16) ushort_t Bs[128 * 32];   // 8KB
  const int tid = threadIdx.x;
  const int m0 = blockIdx.x * 64, n0 = blockIdx.y * 128;
  const int w = tid >> 6, lane = tid & 63, lr = lane & 15, lg = lane >> 4;
  const int wm = (w >> 1) * 32, wn = (w & 1) * 64;

  f32x4 acc[2][4];
#pragma unroll
  for (int i = 0; i < 2; ++i)
#pragma unroll
    for (int j = 0; j < 4; ++j) acc[i][j] = f32x4{0.f, 0.f, 0.f, 0.f};

  const int gr = tid >> 2, gc = (tid & 3) * 8;       // 64 rows x 4 chunks map

  for (int k0 = 0; k0 < K; k0 += 32) {
    gload16(Ap + (size_t)(m0 + gr) * K + k0 + gc,      As + tid*8);
    gload16(Bp + (size_t)(n0 + gr) * K + k0 + gc,      Bs + tid*8);
    gload16(Bp + (size_t)(n0 + 64 + gr) * K + k0 + gc, Bs + 64*32 + tid*8);
    __syncthreads();

    bf16x8 af[2], bfv[4];
#pragma unroll
    for (int i = 0; i < 2; ++i) af[i]  = ld8(&As[(wm + i*16 + lr)*32 + 8*lg]);
#pragma unroll
    for (int j = 0; j < 4; ++j) bfv[j] = ld8(&Bs[(wn + j*16 + lr)*32 + 8*lg]);
#pragma unroll
    for (int i = 0; i < 2; ++i)
#pragma unroll
      for (int j = 0; j < 4; ++j)
        acc[i][j] = mfma16(af[i], bfv[j], acc[i][j]);
    __syncthreads();
  }

#pragma unroll
  for (int i = 0; i < 2; ++i) {
    const int mBase = m0 + wm + i*16 + 4*lg;
#pragma unroll
    for (int j = 0; j < 4; ++j) {
      const int n = n0 + wn + j*16 + lr;
      float vv[4];
#pragma unroll
      for (int r = 0; r < 4; ++r) {
        const int m = mBase + r;
        float v = acc[i][j][r];
        if (BIAS == 2) v += bias[n];
        if (BIAS == 1) v += bias[m];
        if (EPI == 1)  v = mask[m] ? v : 0.f;
        if (EPI == 2)  v = 0.5f * v * (1.f + erff(v * 0.70710678118654752f));
        vv[r] = v;
      }
      if (OUTMODE == 0) {
#pragma unroll
        for (int r = 0; r < 4; ++r)
          ((ushort_t*)Cp)[(size_t)(mBase + r) * N + n] = f2bf(vv[r]);
      } else if (OUTMODE == 1) {
#pragma unroll
        for (int r = 0; r < 4; ++r)
          ((float*)Cp)[(size_t)(mBase + r) * N + n] = vv[r];
      } else if (OUTMODE == 2) {       // Ct[b][n][s], s=m-b*S_ (K/V proj path)
        const int bb = mBase >> 11;
        const int sb = mBase & (S_ - 1);
        ushort_t t4[4] = { f2bf(vv[0]), f2bf(vv[1]), f2bf(vv[2]), f2bf(vv[3]) };
        *reinterpret_cast<short4_t*>(
            (ushort_t*)Cp + ((size_t)bb * D_ + n) * S_ + sb) =
            *reinterpret_cast<short4_t*>(t4);
      } else {                         // Ct[n][m], stride M (linproj V path)
        ushort_t t4[4] = { f2bf(vv[0]), f2bf(vv[1]), f2bf(vv[2]), f2bf(vv[3]) };
        *reinterpret_cast<short4_t*>(
            (ushort_t*)Cp + (size_t)n * M + mBase) =
            *reinterpret_cast<short4_t*>(t4);
      }
    }
  }
}

// --------------------------- kernel wrappers -------------------------------
__global__ __launch_bounds__(256) void k_kv(
    const float* __restrict__ bk, const float* __restrict__ bv,
    const int* __restrict__ mask, const ushort_t* __restrict__ ws,
    ushort_t* __restrict__ KbT, ushort_t* __restrict__ VbT)
{
  if (blockIdx.z == 0)
    gemmT<2, 1, 2>(ws + XK_OFF, ws + WK_OFF, bk, mask, KbT, B_*S_, D_, D_);
  else
    gemmT<2, 1, 2>(ws + XV_OFF, ws + WV_OFF, bv, mask, VbT, B_*S_, D_, D_);
}

__global__ __launch_bounds__(256) void k_q(
    const float* __restrict__ bq, const int* __restrict__ mask,
    const ushort_t* __restrict__ ws, ushort_t* __restrict__ Qb)
{
  gemmT<2, 1, 0>(ws + XQ_OFF, ws + WQ_OFF, bq, mask, Qb, B_*S_, D_, D_);
}

__global__ __launch_bounds__(256) void k_linproj(
    const float* __restrict__ bkP, const float* __restrict__ bvP,
    const ushort_t* __restrict__ ws, const ushort_t* __restrict__ KbT,
    const ushort_t* __restrict__ VbT, ushort_t* __restrict__ Kp,
    ushort_t* __restrict__ VpT)
{
  const int z = blockIdx.z, b = z >> 1, isv = z & 1;
  if (isv) {
    gemmT<1, 2, 3>(ws + WVPB_OFF, VbT + (size_t)b * D_ * S_, bvP,
                   nullptr, VpT + (size_t)b * D_ * SP_, SP_, D_, S_);
  } else {
    gemmT<1, 2, 0>(ws + WKPB_OFF, KbT + (size_t)b * D_ * S_, bkP,
                   nullptr, Kp + (size_t)b * SP_ * D_, SP_, D_, S_);
  }
}

__global__ __launch_bounds__(256) void k_outproj(
    const ushort_t* __restrict__ Xo, const ushort_t* __restrict__ Wob,
    const float* __restrict__ bo, float* __restrict__ out)
{
  gemmT<2, 0, 1>(Xo, Wob, bo, nullptr, out, B_*S_, D_, D_);
}

// ---------------------------------------------------------------------------
// Fused attention (round-9 structure, unchanged): 512 thr, QBLK=128, KVBLK=64,
// LDS-staged K/V^T (gload, dbuf, XOR swizzle), fixed-max softmax.
// ---------------------------------------------------------------------------
__global__ __launch_bounds__(512) void attn_kernel(
    const ushort_t* __restrict__ Qb, const ushort_t* __restrict__ Kp,
    const ushort_t* __restrict__ VpT, ushort_t* __restrict__ Xo)
{
  __shared__ __align__(16) ushort_t Ks[2][64 * 64];
  __shared__ __align__(16) ushort_t Vs[2][64 * 64];
  __shared__ __align__(16) ushort_t Pl[8][16][72];

  const int b = blockIdx.z, h = blockIdx.y, s0 = blockIdx.x * 128;
  const int tid = threadIdx.x, w = tid >> 6, lane = tid & 63;
  const int lr = lane & 15, lg = lane >> 4;

  const ushort_t* qp = Qb + (size_t)(b * S_ + s0 + w*16 + lr) * D_ + h * 64;
  const bf16x8 aq0 = ld8(qp + 8*lg);
  const bf16x8 aq1 = ld8(qp + 32 + 8*lg);

  const ushort_t* kbase = Kp  + (size_t)b * SP_ * D_ + h * 64;
  const ushort_t* vbase = VpT + (size_t)b * D_ * SP_ + (size_t)(h*64) * SP_;

  const int srow = tid >> 3, sch = tid & 7;
  const int schx = (sch ^ (srow & 7)) << 3;

  f32x4 o[4];
#pragma unroll
  for (int dt = 0; dt < 4; ++dt) o[dt] = f32x4{0.f, 0.f, 0.f, 0.f};
  float lsum[4] = {0.f, 0.f, 0.f, 0.f};
  constexpr float C_ = 0.18033688011112042f;          // 0.125 * log2(e)

  gload16(kbase + (size_t)srow * D_ + schx, Ks[0] + tid*8);
  gload16(vbase + (size_t)srow * SP_ + schx, Vs[0] + tid*8);
  __syncthreads();

  int cur = 0;
  for (int pt = 0; pt < SP_ / 64; ++pt) {
    if (pt + 1 < SP_ / 64) {
      const int p1 = (pt + 1) * 64;
      gload16(kbase + (size_t)(p1 + srow) * D_ + schx, Ks[cur^1] + tid*8);
      gload16(vbase + (size_t)srow * SP_ + p1 + schx, Vs[cur^1] + tid*8);
    }

    const int rk7 = lr & 7;
#pragma unroll
    for (int nt = 0; nt < 4; ++nt) {
      const ushort_t* krow = Ks[cur] + (nt*16 + lr) * 64;
      f32x4 a = f32x4{0.f, 0.f, 0.f, 0.f};
      a = mfma16(aq0, ld8(krow + ((lg       ^ rk7) << 3)), a);
      a = mfma16(aq1, ld8(krow + (((4 + lg) ^ rk7) << 3)), a);
#pragma unroll
      for (int r = 0; r < 4; ++r) {
        const float p = __builtin_exp2f(a[r] * C_);
        lsum[r] += p;
        Pl[w][4*lg + r][nt*16 + lr] =
            __builtin_bit_cast(ushort_t, __float2bfloat16(p));
      }
    }

    const bf16x8 pa0 = ld8(&Pl[w][lr][8*lg]);
    const bf16x8 pa1 = ld8(&Pl[w][lr][32 + 8*lg]);
#pragma unroll
    for (int dt = 0; dt < 4; ++dt) {
      const ushort_t* vrow = Vs[cur] + (dt*16 + lr) * 64;
      o[dt] = mfma16(pa0, ld8(vrow + ((lg       ^ rk7) << 3)), o[dt]);
      o[dt] = mfma16(pa1, ld8(vrow + (((4 + lg) ^ rk7) << 3)), o[dt]);
    }

    __syncthreads();
    cur ^= 1;
  }

#pragma unroll
  for (int r = 0; r < 4; ++r) {
#pragma unroll
    for (int off2 = 1; off2 < 16; off2 <<= 1)
      lsum[r] += __shfl_xor(lsum[r], off2, 64);
    lsum[r] = 1.f / lsum[r];
  }

#pragma unroll
  for (int dt = 0; dt < 4; ++dt)
#pragma unroll
    for (int r = 0; r < 4; ++r) {
      const int srow2 = s0 + w*16 + 4*lg + r;
      Xo[(size_t)(b * S_ + srow2) * D_ + h*64 + dt*16 + lr] =
          f2bf(o[dt][r] * lsum[r]);
    }
}

// ------------------------------- launch ------------------------------------
extern "C" void kernel_launch(void* const* d_in, const int* in_sizes, int n_in,
                              void* d_out, int out_size, void* d_ws, size_t ws_size,
                              hipStream_t stream)
{
  const float* q   = (const float*)d_in[0];
  const float* k   = (const float*)d_in[1];
  const float* v   = (const float*)d_in[2];
  const int*   msk = (const int*)d_in[3];
  const float* Wq  = (const float*)d_in[4];
  const float* bq  = (const float*)d_in[5];
  const float* Wk  = (const float*)d_in[6];
  const float* bk  = (const float*)d_in[7];
  const float* Wv  = (const float*)d_in[8];
  const float* bv  = (const float*)d_in[9];
  const float* Wo  = (const float*)d_in[10];
  const float* bo  = (const float*)d_in[11];
  const float* WkP = (const float*)d_in[12];
  const float* bkP = (const float*)d_in[13];
  const float* WvP = (const float*)d_in[14];
  const float* bvP = (const float*)d_in[15];

  ushort_t* ws  = (ushort_t*)d_ws;
  ushort_t* Qb  = ws + QB_OFF;
  ushort_t* Kp  = ws + KP_OFF;
  ushort_t* VpT = ws + VPT_OFF;
  ushort_t* Xo  = ws + XO_OFF;
  ushort_t* KbT = (ushort_t*)d_out;     // d_out as scratch until k_outproj
  ushort_t* VbT = KbT + 4 * M1;

  dim3 blk(256, 1, 1);
  k_convert_a<<<dim3(8192, 1, 1), blk, 0, stream>>>(q, k, v, Wq, Wk, Wv, Wo, ws);
  k_kv     <<<dim3(B_*S_/64, D_/128, 2), blk, 0, stream>>>(bk, bv, msk, ws, KbT, VbT);
  k_q      <<<dim3(B_*S_/64, D_/128, 1), blk, 0, stream>>>(bq, msk, ws, Qb);
  k_convert_b<<<dim3(2048, 1, 1), blk, 0, stream>>>(WkP, WvP, ws);
  k_linproj<<<dim3(SP_/64,  D_/128, 4), blk, 0, stream>>>(bkP, bvP, ws, KbT, VbT, Kp, VpT);
  attn_kernel<<<dim3(S_/128, H_, B_), dim3(512,1,1), 0, stream>>>(Qb, Kp, VpT, Xo);
  k_outproj<<<dim3(B_*S_/64, D_/128, 1), blk, 0, stream>>>(Xo, ws + WO_OFF, bo, (float*)d_out);
}

// Round 13
// 163.657 us; speedup vs baseline: 1.1257x; 1.0461x over previous
//
#include <hip/hip_runtime.h>
#include <hip/hip_bf16.h>

// Linformer MHA, MI355X gfx950. Round 13:
//   attn: swapped QK^T (S^T: q in lanes, p in regs) -> cvt_pk bf16 pairs ->
//         4x ds_write_b64 per tile (was 16x ds_write_u16), scalar denominator.
//   gemmT: + bijective XCD swizzle (x-band per XCD -> A+B ~L2-resident).
// Pipeline (stream-ordered aliasing, ws = 32MB exactly):
//   k_convert_a: q,k,v -> Xqb[0:4M) Xkb[4M:8M) Xvb[8M:12M); Wq/Wk/Wv/Wo -> [12M:16M)
//   k_kv   : K/V projections -> KbT/VbT in d_out
//   k_q    : Q projection -> Qb @ [4M:8M)
//   k_convert_b: WkP/WvP -> [8M:12M)
//   k_linproj: -> Kp[0:2M) VpT[2M:4M)
//   attn   : -> Xo[8M:12M)
//   k_outproj: -> fp32 d_out

typedef __attribute__((ext_vector_type(4))) float  f32x4;
typedef __attribute__((ext_vector_type(8))) short  short8;
typedef __attribute__((ext_vector_type(4))) short  short4_t;
typedef __attribute__((ext_vector_type(2))) unsigned int uint32x2;
typedef __attribute__((ext_vector_type(8))) __bf16 bf16x8;
typedef unsigned short ushort_t;

#define DEV __device__ __forceinline__

constexpr int B_ = 2, S_ = 2048, D_ = 1024, H_ = 16, SP_ = 1024;
constexpr size_t M1 = 1u << 20;
constexpr size_t XQ_OFF = 0,      XK_OFF = 4*M1,  XV_OFF = 8*M1,
                 WQ_OFF = 12*M1,  WK_OFF = 13*M1, WV_OFF = 14*M1, WO_OFF = 15*M1,
                 QB_OFF = 4*M1,   KP_OFF = 0,     VPT_OFF = 2*M1,
                 WKPB_OFF = 8*M1, WVPB_OFF = 10*M1, XO_OFF = 8*M1;

DEV ushort_t f2bf(float f) {              // RNE fp32 -> bf16 bits
  unsigned u = __builtin_bit_cast(unsigned, f);
  unsigned r = ((u >> 16) & 1u) + 0x7FFFu;
  return (ushort_t)((u + r) >> 16);
}
DEV bf16x8 ld8(const ushort_t* p) {
  return __builtin_bit_cast(bf16x8, *reinterpret_cast<const short8*>(p));
}
DEV f32x4 mfma16(bf16x8 a, bf16x8 b, f32x4 c) {
  return __builtin_amdgcn_mfma_f32_16x16x32_bf16(a, b, c, 0, 0, 0);
}
DEV void gload16(const ushort_t* g, ushort_t* l) {   // 16B global -> LDS direct
  __builtin_amdgcn_global_load_lds(
      (const __attribute__((address_space(1))) void*)g,
      (__attribute__((address_space(3))) void*)l, 16, 0, 0);
}
DEV void cvt2048(const float* src, ushort_t* dst, int tid) {
  const size_t off = (size_t)tid * 8;
  float4 f0 = *reinterpret_cast<const float4*>(src + off);
  float4 f1 = *reinterpret_cast<const float4*>(src + off + 4);
  ushort_t t[8] = { f2bf(f0.x), f2bf(f0.y), f2bf(f0.z), f2bf(f0.w),
                    f2bf(f1.x), f2bf(f1.y), f2bf(f1.z), f2bf(f1.w) };
  *reinterpret_cast<short8*>(dst + off) = *reinterpret_cast<short8*>(t);
}

// ---------------------------------------------------------------------------
// Conversion A: q,k,v (12M) + Wq,Wk,Wv,Wo (4M) -> bf16. 8192 blocks x 2048 el.
// ---------------------------------------------------------------------------
__global__ __launch_bounds__(256) void k_convert_a(
    const float* __restrict__ q, const float* __restrict__ k,
    const float* __restrict__ v, const float* __restrict__ Wq,
    const float* __restrict__ Wk, const float* __restrict__ Wv,
    const float* __restrict__ Wo, ushort_t* __restrict__ ws)
{
  int blk = blockIdx.x; const float* src; ushort_t* dst;
  if      (blk < 2048) { src = q;  dst = ws + XQ_OFF; }
  else if (blk < 4096) { src = k;  dst = ws + XK_OFF; blk -= 2048; }
  else if (blk < 6144) { src = v;  dst = ws + XV_OFF; blk -= 4096; }
  else if (blk < 6656) { src = Wq; dst = ws + WQ_OFF; blk -= 6144; }
  else if (blk < 7168) { src = Wk; dst = ws + WK_OFF; blk -= 6656; }
  else if (blk < 7680) { src = Wv; dst = ws + WV_OFF; blk -= 7168; }
  else                 { src = Wo; dst = ws + WO_OFF; blk -= 7680; }
  cvt2048(src + (size_t)blk * 2048, dst + (size_t)blk * 2048, threadIdx.x);
}

// Conversion B: WkP, WvP (4M elems) -> bf16. 2048 blocks.
__global__ __launch_bounds__(256) void k_convert_b(
    const float* __restrict__ WkP, const float* __restrict__ WvP,
    ushort_t* __restrict__ ws)
{
  int blk = blockIdx.x; const float* src; ushort_t* dst;
  if (blk < 1024) { src = WkP; dst = ws + WKPB_OFF; }
  else            { src = WvP; dst = ws + WVPB_OFF; blk -= 1024; }
  cvt2048(src + (size_t)blk * 2048, dst + (size_t)blk * 2048, threadIdx.x);
}

// ---------------------------------------------------------------------------
// 64x128x(K) bf16 MFMA GEMM, 256 thr (4 waves), single-buffered linear LDS,
// global_load_lds both operands, bijective XCD swizzle (x-band per XCD).
// OUTMODE: 0 bf16 C[m][n]; 1 fp32 C[m][n]; 2 bf16 Ct[b][n][s] (s strided S_);
//          3 bf16 Ct[n][m] (stride M).
// ---------------------------------------------------------------------------
template<int BIAS, int EPI, int OUTMODE>
DEV void gemmT(const ushort_t* Ap, const ushort_t* Bp, const float* bias,
               const int* mask, void* Cp, int M, int N, int K)
{
  __shared__ __align__(16) ushort_t As[64 * 32];    // 4KB
  __shared__ __align__(16) ushort_t Bs[128 * 32];   // 8KB
  const int tid = threadIdx.x;

  // XCD swizzle: nwg%8==0 for all grids here; XCD (= lin%8 round-robin) gets
  // a contiguous wg range; y-fastest decomposition -> x-band per XCD.
  const int gx = gridDim.x, gy = gridDim.y, nwg = gx * gy;
  int lin = blockIdx.y * gx + blockIdx.x;
  lin = (lin & 7) * (nwg >> 3) + (lin >> 3);
  const int m0 = (lin / gy) * 64, n0 = (lin % gy) * 128;

  const int w = tid >> 6, lane = tid & 63, lr = lane & 15, lg = lane >> 4;
  const int wm = (w >> 1) * 32, wn = (w & 1) * 64;

  f32x4 acc[2][4];
#pragma unroll
  for (int i = 0; i < 2; ++i)
#pragma unroll
    for (int j = 0; j < 4; ++j) acc[i][j] = f32x4{0.f, 0.f, 0.f, 0.f};

  const int gr = tid >> 2, gc = (tid & 3) * 8;       // 64 rows x 4 chunks map

  for (int k0 = 0; k0 < K; k0 += 32) {
    gload16(Ap + (size_t)(m0 + gr) * K + k0 + gc,      As + tid*8);
    gload16(Bp + (size_t)(n0 + gr) * K + k0 + gc,      Bs + tid*8);
    gload16(Bp + (size_t)(n0 + 64 + gr) * K + k0 + gc, Bs + 64*32 + tid*8);
    __syncthreads();

    bf16x8 af[2], bfv[4];
#pragma unroll
    for (int i = 0; i < 2; ++i) af[i]  = ld8(&As[(wm + i*16 + lr)*32 + 8*lg]);
#pragma unroll
    for (int j = 0; j < 4; ++j) bfv[j] = ld8(&Bs[(wn + j*16 + lr)*32 + 8*lg]);
#pragma unroll
    for (int i = 0; i < 2; ++i)
#pragma unroll
      for (int j = 0; j < 4; ++j)
        acc[i][j] = mfma16(af[i], bfv[j], acc[i][j]);
    __syncthreads();
  }

#pragma unroll
  for (int i = 0; i < 2; ++i) {
    const int mBase = m0 + wm + i*16 + 4*lg;
#pragma unroll
    for (int j = 0; j < 4; ++j) {
      const int n = n0 + wn + j*16 + lr;
      float vv[4];
#pragma unroll
      for (int r = 0; r < 4; ++r) {
        const int m = mBase + r;
        float v = acc[i][j][r];
        if (BIAS == 2) v += bias[n];
        if (BIAS == 1) v += bias[m];
        if (EPI == 1)  v = mask[m] ? v : 0.f;
        if (EPI == 2)  v = 0.5f * v * (1.f + erff(v * 0.70710678118654752f));
        vv[r] = v;
      }
      if (OUTMODE == 0) {
#pragma unroll
        for (int r = 0; r < 4; ++r)
          ((ushort_t*)Cp)[(size_t)(mBase + r) * N + n] = f2bf(vv[r]);
      } else if (OUTMODE == 1) {
#pragma unroll
        for (int r = 0; r < 4; ++r)
          ((float*)Cp)[(size_t)(mBase + r) * N + n] = vv[r];
      } else if (OUTMODE == 2) {       // Ct[b][n][s], s=m-b*S_ (K/V proj path)
        const int bb = mBase >> 11;
        const int sb = mBase & (S_ - 1);
        ushort_t t4[4] = { f2bf(vv[0]), f2bf(vv[1]), f2bf(vv[2]), f2bf(vv[3]) };
        *reinterpret_cast<short4_t*>(
            (ushort_t*)Cp + ((size_t)bb * D_ + n) * S_ + sb) =
            *reinterpret_cast<short4_t*>(t4);
      } else {                         // Ct[n][m], stride M (linproj V path)
        ushort_t t4[4] = { f2bf(vv[0]), f2bf(vv[1]), f2bf(vv[2]), f2bf(vv[3]) };
        *reinterpret_cast<short4_t*>(
            (ushort_t*)Cp + (size_t)n * M + mBase) =
            *reinterpret_cast<short4_t*>(t4);
      }
    }
  }
}

// --------------------------- kernel wrappers -------------------------------
__global__ __launch_bounds__(256) void k_kv(
    const float* __restrict__ bk, const float* __restrict__ bv,
    const int* __restrict__ mask, const ushort_t* __restrict__ ws,
    ushort_t* __restrict__ KbT, ushort_t* __restrict__ VbT)
{
  if (blockIdx.z == 0)
    gemmT<2, 1, 2>(ws + XK_OFF, ws + WK_OFF, bk, mask, KbT, B_*S_, D_, D_);
  else
    gemmT<2, 1, 2>(ws + XV_OFF, ws + WV_OFF, bv, mask, VbT, B_*S_, D_, D_);
}

__global__ __launch_bounds__(256) void k_q(
    const float* __restrict__ bq, const int* __restrict__ mask,
    const ushort_t* __restrict__ ws, ushort_t* __restrict__ Qb)
{
  gemmT<2, 1, 0>(ws + XQ_OFF, ws + WQ_OFF, bq, mask, Qb, B_*S_, D_, D_);
}

__global__ __launch_bounds__(256) void k_linproj(
    const float* __restrict__ bkP, const float* __restrict__ bvP,
    const ushort_t* __restrict__ ws, const ushort_t* __restrict__ KbT,
    const ushort_t* __restrict__ VbT, ushort_t* __restrict__ Kp,
    ushort_t* __restrict__ VpT)
{
  const int z = blockIdx.z, b = z >> 1, isv = z & 1;
  if (isv) {
    gemmT<1, 2, 3>(ws + WVPB_OFF, VbT + (size_t)b * D_ * S_, bvP,
                   nullptr, VpT + (size_t)b * D_ * SP_, SP_, D_, S_);
  } else {
    gemmT<1, 2, 0>(ws + WKPB_OFF, KbT + (size_t)b * D_ * S_, bkP,
                   nullptr, Kp + (size_t)b * SP_ * D_, SP_, D_, S_);
  }
}

__global__ __launch_bounds__(256) void k_outproj(
    const ushort_t* __restrict__ Xo, const ushort_t* __restrict__ Wob,
    const float* __restrict__ bo, float* __restrict__ out)
{
  gemmT<2, 0, 1>(Xo, Wob, bo, nullptr, out, B_*S_, D_, D_);
}

// ---------------------------------------------------------------------------
// Fused attention v6: 512 thr (8 waves x 16 q-rows), KVBLK=64, LDS-staged
// K/V^T (gload, dbuf, XOR swizzle). SWAPPED QK^T: S^T = mfma(K_frag, Q_frag)
// puts q in lanes (col=lane&15), p in regs (row=4*lg+r) -> P pairs packed
// with v_cvt_pk_bf16_f32, written as 4x ds_write_b64/tile; denominator is a
// per-lane scalar (q fixed per lane), reduced once at the end.
// ---------------------------------------------------------------------------
__global__ __launch_bounds__(512) void attn_kernel(
    const ushort_t* __restrict__ Qb, const ushort_t* __restrict__ Kp,
    const ushort_t* __restrict__ VpT, ushort_t* __restrict__ Xo)
{
  __shared__ __align__(16) ushort_t Ks[2][64 * 64];
  __shared__ __align__(16) ushort_t Vs[2][64 * 64];
  __shared__ __align__(16) ushort_t Pl[8][16][72];   // per-wave P [q][p+pad]

  const int b = blockIdx.z, h = blockIdx.y, s0 = blockIdx.x * 128;
  const int tid = threadIdx.x, w = tid >> 6, lane = tid & 63;
  const int lr = lane & 15, lg = lane >> 4;

  const ushort_t* qp = Qb + (size_t)(b * S_ + s0 + w*16 + lr) * D_ + h * 64;
  const bf16x8 aq0 = ld8(qp + 8*lg);        // d = 0..31 slice
  const bf16x8 aq1 = ld8(qp + 32 + 8*lg);   // d = 32..63 slice

  const ushort_t* kbase = Kp  + (size_t)b * SP_ * D_ + h * 64;
  const ushort_t* vbase = VpT + (size_t)b * D_ * SP_ + (size_t)(h*64) * SP_;

  const int srow = tid >> 3, sch = tid & 7;
  const int schx = (sch ^ (srow & 7)) << 3;

  f32x4 o[4];
#pragma unroll
  for (int dt = 0; dt < 4; ++dt) o[dt] = f32x4{0.f, 0.f, 0.f, 0.f};
  float lsum4[4] = {0.f, 0.f, 0.f, 0.f};    // per-lane (q=lr) partial denoms
  constexpr float C_ = 0.18033688011112042f;          // 0.125 * log2(e)

  gload16(kbase + (size_t)srow * D_ + schx, Ks[0] + tid*8);
  gload16(vbase + (size_t)srow * SP_ + schx, Vs[0] + tid*8);
  __syncthreads();

  int cur = 0;
  for (int pt = 0; pt < SP_ / 64; ++pt) {
    if (pt + 1 < SP_ / 64) {
      const int p1 = (pt + 1) * 64;
      gload16(kbase + (size_t)(p1 + srow) * D_ + schx, Ks[cur^1] + tid*8);
      gload16(vbase + (size_t)srow * SP_ + p1 + schx, Vs[cur^1] + tid*8);
    }

    const int rk7 = lr & 7;
    // ---- S^T = K Q^T (swapped); P packed to bf16 pairs; 1 b64 write/nt ----
#pragma unroll
    for (int nt = 0; nt < 4; ++nt) {
      const ushort_t* krow = Ks[cur] + (nt*16 + lr) * 64;   // p-row = nt*16+lr
      f32x4 a = f32x4{0.f, 0.f, 0.f, 0.f};
      a = mfma16(ld8(krow + ((lg       ^ rk7) << 3)), aq0, a);
      a = mfma16(ld8(krow + (((4 + lg) ^ rk7) << 3)), aq1, a);
      const float e0 = __builtin_exp2f(a[0] * C_);
      const float e1 = __builtin_exp2f(a[1] * C_);
      const float e2 = __builtin_exp2f(a[2] * C_);
      const float e3 = __builtin_exp2f(a[3] * C_);
      lsum4[nt] += (e0 + e1) + (e2 + e3);
      unsigned p01, p23;
      asm("v_cvt_pk_bf16_f32 %0, %1, %2" : "=v"(p01) : "v"(e0), "v"(e1));
      asm("v_cvt_pk_bf16_f32 %0, %1, %2" : "=v"(p23) : "v"(e2), "v"(e3));
      uint32x2 pw; pw[0] = p01; pw[1] = p23;
      // P[q=lr][p = nt*16 + 4*lg + 0..3]  (8B-aligned: (32nt+8lg)B, row 144B)
      *reinterpret_cast<uint32x2*>(&Pl[w][lr][nt*16 + 4*lg]) = pw;
    }

    // ---- O += P @ V (A-frag: q=lane&15 row, k=p=8*lg+j -> contiguous) ----
    const bf16x8 pa0 = ld8(&Pl[w][lr][8*lg]);        // p = 0..31 slice
    const bf16x8 pa1 = ld8(&Pl[w][lr][32 + 8*lg]);   // p = 32..63 slice
#pragma unroll
    for (int dt = 0; dt < 4; ++dt) {
      const ushort_t* vrow = Vs[cur] + (dt*16 + lr) * 64;
      o[dt] = mfma16(pa0, ld8(vrow + ((lg       ^ rk7) << 3)), o[dt]);
      o[dt] = mfma16(pa1, ld8(vrow + (((4 + lg) ^ rk7) << 3)), o[dt]);
    }

    __syncthreads();
    cur ^= 1;
  }

  // ---- denominator: reduce the 4 lane-groups (same q=lr), then broadcast ----
  float lsum = (lsum4[0] + lsum4[1]) + (lsum4[2] + lsum4[3]);
  lsum += __shfl_xor(lsum, 16, 64);
  lsum += __shfl_xor(lsum, 32, 64);          // every lane: total for q=lr
  float linv[4];
#pragma unroll
  for (int r = 0; r < 4; ++r)
    linv[r] = 1.f / __shfl(lsum, 4*lg + r, 64);   // lane (4lg+r) has q=4lg+r

#pragma unroll
  for (int dt = 0; dt < 4; ++dt)
#pragma unroll
    for (int r = 0; r < 4; ++r) {
      const int srow2 = s0 + w*16 + 4*lg + r;
      Xo[(size_t)(b * S_ + srow2) * D_ + h*64 + dt*16 + lr] =
          f2bf(o[dt][r] * linv[r]);
    }
}

// ------------------------------- launch ------------------------------------
extern "C" void kernel_launch(void* const* d_in, const int* in_sizes, int n_in,
                              void* d_out, int out_size, void* d_ws, size_t ws_size,
                              hipStream_t stream)
{
  const float* q   = (const float*)d_in[0];
  const float* k   = (const float*)d_in[1];
  const float* v   = (const float*)d_in[2];
  const int*   msk = (const int*)d_in[3];
  const float* Wq  = (const float*)d_in[4];
  const float* bq  = (const float*)d_in[5];
  const float* Wk  = (const float*)d_in[6];
  const float* bk  = (const float*)d_in[7];
  const float* Wv  = (const float*)d_in[8];
  const float* bv  = (const float*)d_in[9];
  const float* Wo  = (const float*)d_in[10];
  const float* bo  = (const float*)d_in[11];
  const float* WkP = (const float*)d_in[12];
  const float* bkP = (const float*)d_in[13];
  const float* WvP = (const float*)d_in[14];
  const float* bvP = (const float*)d_in[15];

  ushort_t* ws  = (ushort_t*)d_ws;
  ushort_t* Qb  = ws + QB_OFF;
  ushort_t* Kp  = ws + KP_OFF;
  ushort_t* VpT = ws + VPT_OFF;
  ushort_t* Xo  = ws + XO_OFF;
  ushort_t* KbT = (ushort_t*)d_out;     // d_out as scratch until k_outproj
  ushort_t* VbT = KbT + 4 * M1;

  dim3 blk(256, 1, 1);
  k_convert_a<<<dim3(8192, 1, 1), blk, 0, stream>>>(q, k, v, Wq, Wk, Wv, Wo, ws);
  k_kv     <<<dim3(B_*S_/64, D_/128, 2), blk, 0, stream>>>(bk, bv, msk, ws, KbT, VbT);
  k_q      <<<dim3(B_*S_/64, D_/128, 1), blk, 0, stream>>>(bq, msk, ws, Qb);
  k_convert_b<<<dim3(2048, 1, 1), blk, 0, stream>>>(WkP, WvP, ws);
  k_linproj<<<dim3(SP_/64,  D_/128, 4), blk, 0, stream>>>(bkP, bvP, ws, KbT, VbT, Kp, VpT);
  attn_kernel<<<dim3(S_/128, H_, B_), dim3(512,1,1), 0, stream>>>(Qb, Kp, VpT, Xo);
  k_outproj<<<dim3(B_*S_/64, D_/128, 1), blk, 0, stream>>>(Xo, ws + WO_OFF, bo, (float*)d_out);
}

// Round 14
// 148.534 us; speedup vs baseline: 1.2403x; 1.1018x over previous
//
#include <hip/hip_runtime.h>
#include <hip/hip_bf16.h>

// Linformer MHA, MI355X gfx950. Round 14: gemmT BK 32->64 (half the barriers,
// 2x MFMA/step) + T2 XOR swizzle on the 128B-row LDS tiles (same swizzle the
// attn kernel has used since round 9). Everything else = round 13.
// Pipeline (stream-ordered aliasing, ws = 32MB exactly):
//   k_convert_a: q,k,v -> Xqb[0:4M) Xkb[4M:8M) Xvb[8M:12M); Wq/Wk/Wv/Wo -> [12M:16M)
//   k_kv   : K/V projections -> KbT/VbT in d_out
//   k_q    : Q projection -> Qb @ [4M:8M)
//   k_convert_b: WkP/WvP -> [8M:12M)
//   k_linproj: -> Kp[0:2M) VpT[2M:4M)
//   attn   : -> Xo[8M:12M)
//   k_outproj: -> fp32 d_out

typedef __attribute__((ext_vector_type(4))) float  f32x4;
typedef __attribute__((ext_vector_type(8))) short  short8;
typedef __attribute__((ext_vector_type(4))) short  short4_t;
typedef __attribute__((ext_vector_type(2))) unsigned int uint32x2;
typedef __attribute__((ext_vector_type(8))) __bf16 bf16x8;
typedef unsigned short ushort_t;

#define DEV __device__ __forceinline__

constexpr int B_ = 2, S_ = 2048, D_ = 1024, H_ = 16, SP_ = 1024;
constexpr size_t M1 = 1u << 20;
constexpr size_t XQ_OFF = 0,      XK_OFF = 4*M1,  XV_OFF = 8*M1,
                 WQ_OFF = 12*M1,  WK_OFF = 13*M1, WV_OFF = 14*M1, WO_OFF = 15*M1,
                 QB_OFF = 4*M1,   KP_OFF = 0,     VPT_OFF = 2*M1,
                 WKPB_OFF = 8*M1, WVPB_OFF = 10*M1, XO_OFF = 8*M1;

DEV ushort_t f2bf(float f) {              // RNE fp32 -> bf16 bits
  unsigned u = __builtin_bit_cast(unsigned, f);
  unsigned r = ((u >> 16) & 1u) + 0x7FFFu;
  return (ushort_t)((u + r) >> 16);
}
DEV bf16x8 ld8(const ushort_t* p) {
  return __builtin_bit_cast(bf16x8, *reinterpret_cast<const short8*>(p));
}
DEV f32x4 mfma16(bf16x8 a, bf16x8 b, f32x4 c) {
  return __builtin_amdgcn_mfma_f32_16x16x32_bf16(a, b, c, 0, 0, 0);
}
DEV void gload16(const ushort_t* g, ushort_t* l) {   // 16B global -> LDS direct
  __builtin_amdgcn_global_load_lds(
      (const __attribute__((address_space(1))) void*)g,
      (__attribute__((address_space(3))) void*)l, 16, 0, 0);
}
DEV void cvt2048(const float* src, ushort_t* dst, int tid) {
  const size_t off = (size_t)tid * 8;
  float4 f0 = *reinterpret_cast<const float4*>(src + off);
  float4 f1 = *reinterpret_cast<const float4*>(src + off + 4);
  ushort_t t[8] = { f2bf(f0.x), f2bf(f0.y), f2bf(f0.z), f2bf(f0.w),
                    f2bf(f1.x), f2bf(f1.y), f2bf(f1.z), f2bf(f1.w) };
  *reinterpret_cast<short8*>(dst + off) = *reinterpret_cast<short8*>(t);
}

// ---------------------------------------------------------------------------
// Conversion A: q,k,v (12M) + Wq,Wk,Wv,Wo (4M) -> bf16. 8192 blocks x 2048 el.
// ---------------------------------------------------------------------------
__global__ __launch_bounds__(256) void k_convert_a(
    const float* __restrict__ q, const float* __restrict__ k,
    const float* __restrict__ v, const float* __restrict__ Wq,
    const float* __restrict__ Wk, const float* __restrict__ Wv,
    const float* __restrict__ Wo, ushort_t* __restrict__ ws)
{
  int blk = blockIdx.x; const float* src; ushort_t* dst;
  if      (blk < 2048) { src = q;  dst = ws + XQ_OFF; }
  else if (blk < 4096) { src = k;  dst = ws + XK_OFF; blk -= 2048; }
  else if (blk < 6144) { src = v;  dst = ws + XV_OFF; blk -= 4096; }
  else if (blk < 6656) { src = Wq; dst = ws + WQ_OFF; blk -= 6144; }
  else if (blk < 7168) { src = Wk; dst = ws + WK_OFF; blk -= 6656; }
  else if (blk < 7680) { src = Wv; dst = ws + WV_OFF; blk -= 7168; }
  else                 { src = Wo; dst = ws + WO_OFF; blk -= 7680; }
  cvt2048(src + (size_t)blk * 2048, dst + (size_t)blk * 2048, threadIdx.x);
}

// Conversion B: WkP, WvP (4M elems) -> bf16. 2048 blocks.
__global__ __launch_bounds__(256) void k_convert_b(
    const float* __restrict__ WkP, const float* __restrict__ WvP,
    ushort_t* __restrict__ ws)
{
  int blk = blockIdx.x; const float* src; ushort_t* dst;
  if (blk < 1024) { src = WkP; dst = ws + WKPB_OFF; }
  else            { src = WvP; dst = ws + WVPB_OFF; blk -= 1024; }
  cvt2048(src + (size_t)blk * 2048, dst + (size_t)blk * 2048, threadIdx.x);
}

// ---------------------------------------------------------------------------
// 64x128xK bf16 MFMA GEMM, 256 thr (4 waves), BK=64, single-buffered LDS
// (As 8KB + Bs 16KB, 128B rows XOR-swizzled: slot s of row r holds source
// chunk s^(r&7); global src pre-swizzled, gload dest linear — rule #21).
// 16 MFMA + 12 ds_read_b128 per K-step; barriers halved vs BK=32.
// OUTMODE: 0 bf16 C[m][n]; 1 fp32 C[m][n]; 2 bf16 Ct[b][n][s] (s strided S_);
//          3 bf16 Ct[n][m] (stride M).
// ---------------------------------------------------------------------------
template<int BIAS, int EPI, int OUTMODE>
DEV void gemmT(const ushort_t* Ap, const ushort_t* Bp, const float* bias,
               const int* mask, void* Cp, int M, int N, int K)
{
  __shared__ __align__(16) ushort_t As[64 * 64];    // 8KB
  __shared__ __align__(16) ushort_t Bs[128 * 64];   // 16KB
  const int tid = threadIdx.x;

  // XCD swizzle (bijective: nwg%8==0 for all grids here), y-fastest decomp.
  const int gx = gridDim.x, gy = gridDim.y, nwg = gx * gy;
  int lin = blockIdx.y * gx + blockIdx.x;
  lin = (lin & 7) * (nwg >> 3) + (lin >> 3);
  const int m0 = (lin / gy) * 64, n0 = (lin % gy) * 128;

  const int w = tid >> 6, lane = tid & 63, lr = lane & 15, lg = lane >> 4;
  const int wm = (w >> 1) * 32, wn = (w & 1) * 64;
  const int rk7 = lr & 7;

  f32x4 acc[2][4];
#pragma unroll
  for (int i = 0; i < 2; ++i)
#pragma unroll
    for (int j = 0; j < 4; ++j) acc[i][j] = f32x4{0.f, 0.f, 0.f, 0.f};

  // staging: thread t -> row 32j + (t>>3), slot t&7; source chunk (t&7)^(row&7)
  const int srow = tid >> 3;                          // 0..31
  const int schx = ((tid & 7) ^ (srow & 7)) * 8;      // pre-swizzled col off
  const ushort_t* Ag = Ap + (size_t)(m0 + srow) * K + schx;
  const ushort_t* Bg = Bp + (size_t)(n0 + srow) * K + schx;

  for (int k0 = 0; k0 < K; k0 += 64) {
    gload16(Ag + k0,                 As + tid*8);
    gload16(Ag + (size_t)32*K + k0,  As + 2048 + tid*8);
    gload16(Bg + k0,                 Bs + tid*8);
    gload16(Bg + (size_t)32*K + k0,  Bs + 2048 + tid*8);
    gload16(Bg + (size_t)64*K + k0,  Bs + 4096 + tid*8);
    gload16(Bg + (size_t)96*K + k0,  Bs + 6144 + tid*8);
    __syncthreads();

#pragma unroll
    for (int ks = 0; ks < 2; ++ks) {
      bf16x8 af[2], bfv[4];
#pragma unroll
      for (int i = 0; i < 2; ++i)
        af[i]  = ld8(&As[(wm + i*16 + lr)*64 + (((ks<<2)|lg) ^ rk7)*8]);
#pragma unroll
      for (int j = 0; j < 4; ++j)
        bfv[j] = ld8(&Bs[(wn + j*16 + lr)*64 + (((ks<<2)|lg) ^ rk7)*8]);
#pragma unroll
      for (int i = 0; i < 2; ++i)
#pragma unroll
        for (int j = 0; j < 4; ++j)
          acc[i][j] = mfma16(af[i], bfv[j], acc[i][j]);
    }
    __syncthreads();
  }

#pragma unroll
  for (int i = 0; i < 2; ++i) {
    const int mBase = m0 + wm + i*16 + 4*lg;
#pragma unroll
    for (int j = 0; j < 4; ++j) {
      const int n = n0 + wn + j*16 + lr;
      float vv[4];
#pragma unroll
      for (int r = 0; r < 4; ++r) {
        const int m = mBase + r;
        float v = acc[i][j][r];
        if (BIAS == 2) v += bias[n];
        if (BIAS == 1) v += bias[m];
        if (EPI == 1)  v = mask[m] ? v : 0.f;
        if (EPI == 2)  v = 0.5f * v * (1.f + erff(v * 0.70710678118654752f));
        vv[r] = v;
      }
      if (OUTMODE == 0) {
#pragma unroll
        for (int r = 0; r < 4; ++r)
          ((ushort_t*)Cp)[(size_t)(mBase + r) * N + n] = f2bf(vv[r]);
      } else if (OUTMODE == 1) {
#pragma unroll
        for (int r = 0; r < 4; ++r)
          ((float*)Cp)[(size_t)(mBase + r) * N + n] = vv[r];
      } else if (OUTMODE == 2) {       // Ct[b][n][s], s=m-b*S_ (K/V proj path)
        const int bb = mBase >> 11;
        const int sb = mBase & (S_ - 1);
        ushort_t t4[4] = { f2bf(vv[0]), f2bf(vv[1]), f2bf(vv[2]), f2bf(vv[3]) };
        *reinterpret_cast<short4_t*>(
            (ushort_t*)Cp + ((size_t)bb * D_ + n) * S_ + sb) =
            *reinterpret_cast<short4_t*>(t4);
      } else {                         // Ct[n][m], stride M (linproj V path)
        ushort_t t4[4] = { f2bf(vv[0]), f2bf(vv[1]), f2bf(vv[2]), f2bf(vv[3]) };
        *reinterpret_cast<short4_t*>(
            (ushort_t*)Cp + (size_t)n * M + mBase) =
            *reinterpret_cast<short4_t*>(t4);
      }
    }
  }
}

// --------------------------- kernel wrappers -------------------------------
__global__ __launch_bounds__(256) void k_kv(
    const float* __restrict__ bk, const float* __restrict__ bv,
    const int* __restrict__ mask, const ushort_t* __restrict__ ws,
    ushort_t* __restrict__ KbT, ushort_t* __restrict__ VbT)
{
  if (blockIdx.z == 0)
    gemmT<2, 1, 2>(ws + XK_OFF, ws + WK_OFF, bk, mask, KbT, B_*S_, D_, D_);
  else
    gemmT<2, 1, 2>(ws + XV_OFF, ws + WV_OFF, bv, mask, VbT, B_*S_, D_, D_);
}

__global__ __launch_bounds__(256) void k_q(
    const float* __restrict__ bq, const int* __restrict__ mask,
    const ushort_t* __restrict__ ws, ushort_t* __restrict__ Qb)
{
  gemmT<2, 1, 0>(ws + XQ_OFF, ws + WQ_OFF, bq, mask, Qb, B_*S_, D_, D_);
}

__global__ __launch_bounds__(256) void k_linproj(
    const float* __restrict__ bkP, const float* __restrict__ bvP,
    const ushort_t* __restrict__ ws, const ushort_t* __restrict__ KbT,
    const ushort_t* __restrict__ VbT, ushort_t* __restrict__ Kp,
    ushort_t* __restrict__ VpT)
{
  const int z = blockIdx.z, b = z >> 1, isv = z & 1;
  if (isv) {
    gemmT<1, 2, 3>(ws + WVPB_OFF, VbT + (size_t)b * D_ * S_, bvP,
                   nullptr, VpT + (size_t)b * D_ * SP_, SP_, D_, S_);
  } else {
    gemmT<1, 2, 0>(ws + WKPB_OFF, KbT + (size_t)b * D_ * S_, bkP,
                   nullptr, Kp + (size_t)b * SP_ * D_, SP_, D_, S_);
  }
}

__global__ __launch_bounds__(256) void k_outproj(
    const ushort_t* __restrict__ Xo, const ushort_t* __restrict__ Wob,
    const float* __restrict__ bo, float* __restrict__ out)
{
  gemmT<2, 0, 1>(Xo, Wob, bo, nullptr, out, B_*S_, D_, D_);
}

// ---------------------------------------------------------------------------
// Fused attention (round-13 structure, unchanged): 512 thr, QBLK=128, KVBLK=64,
// LDS-staged K/V^T (gload, dbuf, XOR swizzle), swapped QK^T + cvt_pk P-pack,
// fixed-max softmax, scalar per-lane denominator.
// ---------------------------------------------------------------------------
__global__ __launch_bounds__(512) void attn_kernel(
    const ushort_t* __restrict__ Qb, const ushort_t* __restrict__ Kp,
    const ushort_t* __restrict__ VpT, ushort_t* __restrict__ Xo)
{
  __shared__ __align__(16) ushort_t Ks[2][64 * 64];
  __shared__ __align__(16) ushort_t Vs[2][64 * 64];
  __shared__ __align__(16) ushort_t Pl[8][16][72];   // per-wave P [q][p+pad]

  const int b = blockIdx.z, h = blockIdx.y, s0 = blockIdx.x * 128;
  const int tid = threadIdx.x, w = tid >> 6, lane = tid & 63;
  const int lr = lane & 15, lg = lane >> 4;

  const ushort_t* qp = Qb + (size_t)(b * S_ + s0 + w*16 + lr) * D_ + h * 64;
  const bf16x8 aq0 = ld8(qp + 8*lg);        // d = 0..31 slice
  const bf16x8 aq1 = ld8(qp + 32 + 8*lg);   // d = 32..63 slice

  const ushort_t* kbase = Kp  + (size_t)b * SP_ * D_ + h * 64;
  const ushort_t* vbase = VpT + (size_t)b * D_ * SP_ + (size_t)(h*64) * SP_;

  const int srow = tid >> 3, sch = tid & 7;
  const int schx = (sch ^ (srow & 7)) << 3;

  f32x4 o[4];
#pragma unroll
  for (int dt = 0; dt < 4; ++dt) o[dt] = f32x4{0.f, 0.f, 0.f, 0.f};
  float lsum4[4] = {0.f, 0.f, 0.f, 0.f};    // per-lane (q=lr) partial denoms
  constexpr float C_ = 0.18033688011112042f;          // 0.125 * log2(e)

  gload16(kbase + (size_t)srow * D_ + schx, Ks[0] + tid*8);
  gload16(vbase + (size_t)srow * SP_ + schx, Vs[0] + tid*8);
  __syncthreads();

  int cur = 0;
  for (int pt = 0; pt < SP_ / 64; ++pt) {
    if (pt + 1 < SP_ / 64) {
      const int p1 = (pt + 1) * 64;
      gload16(kbase + (size_t)(p1 + srow) * D_ + schx, Ks[cur^1] + tid*8);
      gload16(vbase + (size_t)srow * SP_ + p1 + schx, Vs[cur^1] + tid*8);
    }

    const int rk7 = lr & 7;
    // ---- S^T = K Q^T (swapped); P packed to bf16 pairs; 1 b64 write/nt ----
#pragma unroll
    for (int nt = 0; nt < 4; ++nt) {
      const ushort_t* krow = Ks[cur] + (nt*16 + lr) * 64;   // p-row = nt*16+lr
      f32x4 a = f32x4{0.f, 0.f, 0.f, 0.f};
      a = mfma16(ld8(krow + ((lg       ^ rk7) << 3)), aq0, a);
      a = mfma16(ld8(krow + (((4 + lg) ^ rk7) << 3)), aq1, a);
      const float e0 = __builtin_exp2f(a[0] * C_);
      const float e1 = __builtin_exp2f(a[1] * C_);
      const float e2 = __builtin_exp2f(a[2] * C_);
      const float e3 = __builtin_exp2f(a[3] * C_);
      lsum4[nt] += (e0 + e1) + (e2 + e3);
      unsigned p01, p23;
      asm("v_cvt_pk_bf16_f32 %0, %1, %2" : "=v"(p01) : "v"(e0), "v"(e1));
      asm("v_cvt_pk_bf16_f32 %0, %1, %2" : "=v"(p23) : "v"(e2), "v"(e3));
      uint32x2 pw; pw[0] = p01; pw[1] = p23;
      *reinterpret_cast<uint32x2*>(&Pl[w][lr][nt*16 + 4*lg]) = pw;
    }

    // ---- O += P @ V ----
    const bf16x8 pa0 = ld8(&Pl[w][lr][8*lg]);        // p = 0..31 slice
    const bf16x8 pa1 = ld8(&Pl[w][lr][32 + 8*lg]);   // p = 32..63 slice
#pragma unroll
    for (int dt = 0; dt < 4; ++dt) {
      const ushort_t* vrow = Vs[cur] + (dt*16 + lr) * 64;
      o[dt] = mfma16(pa0, ld8(vrow + ((lg       ^ rk7) << 3)), o[dt]);
      o[dt] = mfma16(pa1, ld8(vrow + (((4 + lg) ^ rk7) << 3)), o[dt]);
    }

    __syncthreads();
    cur ^= 1;
  }

  // ---- denominator: reduce 4 lane-groups (same q=lr), then broadcast ----
  float lsum = (lsum4[0] + lsum4[1]) + (lsum4[2] + lsum4[3]);
  lsum += __shfl_xor(lsum, 16, 64);
  lsum += __shfl_xor(lsum, 32, 64);          // every lane: total for q=lr
  float linv[4];
#pragma unroll
  for (int r = 0; r < 4; ++r)
    linv[r] = 1.f / __shfl(lsum, 4*lg + r, 64);   // lane (4lg+r) has q=4lg+r

#pragma unroll
  for (int dt = 0; dt < 4; ++dt)
#pragma unroll
    for (int r = 0; r < 4; ++r) {
      const int srow2 = s0 + w*16 + 4*lg + r;
      Xo[(size_t)(b * S_ + srow2) * D_ + h*64 + dt*16 + lr] =
          f2bf(o[dt][r] * linv[r]);
    }
}

// ------------------------------- launch ------------------------------------
extern "C" void kernel_launch(void* const* d_in, const int* in_sizes, int n_in,
                              void* d_out, int out_size, void* d_ws, size_t ws_size,
                              hipStream_t stream)
{
  const float* q   = (const float*)d_in[0];
  const float* k   = (const float*)d_in[1];
  const float* v   = (const float*)d_in[2];
  const int*   msk = (const int*)d_in[3];
  const float* Wq  = (const float*)d_in[4];
  const float* bq  = (const float*)d_in[5];
  const float* Wk  = (const float*)d_in[6];
  const float* bk  = (const float*)d_in[7];
  const float* Wv  = (const float*)d_in[8];
  const float* bv  = (const float*)d_in[9];
  const float* Wo  = (const float*)d_in[10];
  const float* bo  = (const float*)d_in[11];
  const float* WkP = (const float*)d_in[12];
  const float* bkP = (const float*)d_in[13];
  const float* WvP = (const float*)d_in[14];
  const float* bvP = (const float*)d_in[15];

  ushort_t* ws  = (ushort_t*)d_ws;
  ushort_t* Qb  = ws + QB_OFF;
  ushort_t* Kp  = ws + KP_OFF;
  ushort_t* VpT = ws + VPT_OFF;
  ushort_t* Xo  = ws + XO_OFF;
  ushort_t* KbT = (ushort_t*)d_out;     // d_out as scratch until k_outproj
  ushort_t* VbT = KbT + 4 * M1;

  dim3 blk(256, 1, 1);
  k_convert_a<<<dim3(8192, 1, 1), blk, 0, stream>>>(q, k, v, Wq, Wk, Wv, Wo, ws);
  k_kv     <<<dim3(B_*S_/64, D_/128, 2), blk, 0, stream>>>(bk, bv, msk, ws, KbT, VbT);
  k_q      <<<dim3(B_*S_/64, D_/128, 1), blk, 0, stream>>>(bq, msk, ws, Qb);
  k_convert_b<<<dim3(2048, 1, 1), blk, 0, stream>>>(WkP, WvP, ws);
  k_linproj<<<dim3(SP_/64,  D_/128, 4), blk, 0, stream>>>(bkP, bvP, ws, KbT, VbT, Kp, VpT);
  attn_kernel<<<dim3(S_/128, H_, B_), dim3(512,1,1), 0, stream>>>(Qb, Kp, VpT, Xo);
  k_outproj<<<dim3(B_*S_/64, D_/128, 1), blk, 0, stream>>>(Xo, ws + WO_OFF, bo, (float*)d_out);
}